// Round 11
// baseline (111.527 us; speedup 1.0000x reference)
//
#include <hip/hip_runtime.h>
#include <stdint.h>

typedef __bf16 v8bf __attribute__((ext_vector_type(8)));
typedef float  v4f  __attribute__((ext_vector_type(4)));

__device__ __forceinline__ uint16_t f2bf(float f){
  union { float f; uint32_t u; } v; v.f = f;
  uint32_t r = v.u + 0x7FFFu + ((v.u >> 16) & 1u);
  return (uint16_t)(r >> 16);
}
__device__ __forceinline__ float bf2f(uint16_t u){
  union { uint32_t u; float f; } v; v.u = ((uint32_t)u) << 16; return v.f;
}
__device__ __forceinline__ v4f vzero(){ v4f z = {0.f,0.f,0.f,0.f}; return z; }

// async global->LDS, 16B per lane; LDS dest is wave-uniform base + lane*16
__device__ __forceinline__ void gld16(const uint16_t* __restrict__ g, uint16_t* l){
  __builtin_amdgcn_global_load_lds((const __attribute__((address_space(1))) void*)g,
                                   (__attribute__((address_space(3))) void*)l, 16, 0, 0);
}

// ---- 64x64 bf16 tile staging, LDS row stride 72 (vprep) ----
__device__ __forceinline__ void ld64(uint4 r[2], const uint16_t* __restrict__ g, int ldg, int tid){
  int row = tid >> 2, c = (tid & 3) * 16;
  r[0] = *(const uint4*)(g + (size_t)row * ldg + c);
  r[1] = *(const uint4*)(g + (size_t)row * ldg + c + 8);
}
__device__ __forceinline__ void st64(uint16_t* __restrict__ s, const uint4 r[2], int tid){
  int row = tid >> 2, c = (tid & 3) * 16;
  *(uint4*)(s + row * 72 + c) = r[0];
  *(uint4*)(s + row * 72 + c + 8) = r[1];
}
__device__ __forceinline__ void stage64(uint16_t* s, const uint16_t* g, int ldg, int tid){
  uint4 r[2]; ld64(r, g, ldg, tid); st64(s, r, tid);
}

// ---------------- prep ----------------
__global__ void k_xcast(const float* __restrict__ X, uint16_t* __restrict__ Xb,
                        float* __restrict__ csum){
  int i = (blockIdx.x * 256 + threadIdx.x) * 8;
  float4 a = *(const float4*)(X + i);
  float4 b = *(const float4*)(X + i + 4);
  union { uint16_t h[8]; uint4 v; } o;
  o.h[0]=f2bf(a.x); o.h[1]=f2bf(a.y); o.h[2]=f2bf(a.z); o.h[3]=f2bf(a.w);
  o.h[4]=f2bf(b.x); o.h[5]=f2bf(b.y); o.h[6]=f2bf(b.z); o.h[7]=f2bf(b.w);
  *(uint4*)(Xb + i) = o.v;
  if (blockIdx.x < 64)                       // zero csum (64*1024 f32 = 16384 float4)
    ((float4*)csum)[blockIdx.x * 256 + threadIdx.x] = make_float4(0.f, 0.f, 0.f, 0.f);
}

__global__ void k_weff(const float* __restrict__ Wq, const float* __restrict__ Aq, const float* __restrict__ Bq,
                       const float* __restrict__ Wk, const float* __restrict__ Ak, const float* __restrict__ Bk,
                       const float* __restrict__ Wv, const float* __restrict__ Av, const float* __restrict__ Bv,
                       uint16_t* __restrict__ Wo){
  int y = blockIdx.y;
  const float* W  = (y == 0) ? Wq : (y == 1) ? Wk : Wv;
  const float* A  = (y == 0) ? Aq : (y == 1) ? Ak : Av;
  const float* Bm = (y == 0) ? Bq : (y == 1) ? Bk : Bv;
  int idx = blockIdx.x * 256 + threadIdx.x;
  int f = idx >> 10, k = idx & 1023;
  float acc = W[idx];
  #pragma unroll
  for (int r = 0; r < 16; ++r) acc += Bm[f * 16 + r] * A[r * 1024 + k];
  Wo[(size_t)y * 1048576 + idx] = f2bf(acc);
}

// ---------------- fused QKV projection GEMM (m97 structure + XOR swizzle) ----------------
__global__ __launch_bounds__(256, 4)
void k_gemm(const uint16_t* __restrict__ Ag, const uint16_t* __restrict__ Bg,
            const float* __restrict__ qb, const float* __restrict__ kb,
            const float* __restrict__ vb, uint16_t* __restrict__ Cg){
  __shared__ __align__(16) uint16_t smem[16896];
  uint16_t* As = smem;
  uint16_t* Bs = smem + 8192;
  int tid = threadIdx.x, lane = tid & 63, wid = tid >> 6;
  int l15 = lane & 15, lg = lane >> 4;
  int wr = wid >> 1, wc = wid & 1;
  int bid = blockIdx.x, xcd = bid & 7, idx = bid >> 3;
  int nb = xcd * 96 + idx;
  int mt = nb / 24, nt = nb - mt * 24;
  int m0 = mt * 128, n0 = nt * 128;

  int lr  = lane >> 3;
  int lcs = (((lane & 7) ^ lr)) * 8;
  const uint16_t* Abase = Ag + (size_t)(m0 + wid * 32 + lr) * 1024 + lcs;
  const uint16_t* Bbase = Bg + (size_t)(n0 + wid * 32 + lr) * 1024 + lcs;
  uint16_t* Alds = As + wid * 32 * 64;
  uint16_t* Blds = Bs + wid * 32 * 64;

  int sw = l15 & 7;

  v4f acc[4][4];
  #pragma unroll
  for (int a = 0; a < 4; ++a)
    #pragma unroll
    for (int c = 0; c < 4; ++c) acc[a][c] = vzero();

  for (int kk = 0; kk < 1024; kk += 64){
    __syncthreads();
    #pragma unroll
    for (int i = 0; i < 4; ++i){
      gld16(Abase + (size_t)(i * 8) * 1024 + kk, Alds + i * 8 * 64);
      gld16(Bbase + (size_t)(i * 8) * 1024 + kk, Blds + i * 8 * 64);
    }
    __syncthreads();
    #pragma unroll
    for (int kc = 0; kc < 2; ++kc){
      v8bf af[4], bfr[4];
      int cs = ((kc * 4 + lg) ^ sw) * 8;
      #pragma unroll
      for (int mi = 0; mi < 4; ++mi)
        af[mi] = *(const v8bf*)(As + (wr * 64 + mi * 16 + l15) * 64 + cs);
      #pragma unroll
      for (int nj = 0; nj < 4; ++nj)
        bfr[nj] = *(const v8bf*)(Bs + (wc * 64 + nj * 16 + l15) * 64 + cs);
      #pragma unroll
      for (int mi = 0; mi < 4; ++mi)
        #pragma unroll
        for (int nj = 0; nj < 4; ++nj)
          acc[mi][nj] = __builtin_amdgcn_mfma_f32_16x16x32_bf16(af[mi], bfr[nj], acc[mi][nj], 0, 0, 0);
    }
  }
  __syncthreads();
  uint16_t* Ct = smem;
  #pragma unroll
  for (int nj = 0; nj < 4; ++nj){
    int n = n0 + wc * 64 + nj * 16 + l15;
    float bv_ = (n < 1024) ? qb[n] : (n < 2048) ? kb[n - 1024] : vb[n - 2048];
    #pragma unroll
    for (int mi = 0; mi < 4; ++mi)
      #pragma unroll
      for (int r = 0; r < 4; ++r){
        int ml = wr * 64 + mi * 16 + lg * 4 + r;
        Ct[ml * 132 + wc * 64 + nj * 16 + l15] = f2bf(acc[mi][nj][r] + bv_);
      }
  }
  __syncthreads();
  {
    int row = tid >> 1;
    int c0  = (tid & 1) * 64;
    uint16_t* gp = Cg + (size_t)(m0 + row) * 3072 + n0 + c0;
    const uint16_t* sp = Ct + row * 132 + c0;
    #pragma unroll
    for (int c = 0; c < 8; ++c)
      *(uint4*)(gp + c * 8) = *(const uint4*)(sp + c * 8);
  }
}

// ---------------- k_score: compute S-tiles once; exp; csum; register-direct P dump ----------------
// grid 1024 = (xcd, slot, pr, ph). A=K (rows j), B=Q (rows i): frag col(l15)=i, row(lg*4+r)=j.
// P tile layout in ws: elem (i, j) at i*64 + ((j>>3)^(i&7))*8 + (j&7)  (chunk-XOR swizzled).
__global__ __launch_bounds__(256, 4)
void k_score(const uint16_t* __restrict__ QKVg, float* __restrict__ csum,
             uint16_t* __restrict__ Pws){
  __shared__ __align__(16) uint16_t Ka[4096], Kb2[4096], Qs[4096];
  int tid = threadIdx.x, lane = tid & 63, wid = tid >> 6;
  int l15 = lane & 15, lg = lane >> 4;
  int wr = wid >> 1, wc = wid & 1;
  int sw = l15 & 7;
  int bid = blockIdx.x, xcd = bid & 7, idx = bid >> 3;
  int bh = xcd * 8 + (idx & 7);
  int rest = idx >> 3;
  int pr = rest & 7, ph = rest >> 3;
  int b = bh >> 4, h = bh & 15;
  int jtA = pr, jtB = 15 - pr;
  const uint16_t* Qb = QKVg + (size_t)b * 1024 * 3072 + h * 64;
  const uint16_t* Kb = QKVg + (size_t)b * 1024 * 3072 + 1024 + h * 64;
  uint16_t* Pbh = Pws + (size_t)bh * 557056;

  int lr  = lane >> 3;
  int lcs = ((lane & 7) ^ lr) * 8;           // pre-swizzled source chunk
  {                                           // stage K tiles once (swizzled image, gld16)
    const uint16_t* sA = Kb + (size_t)(jtA * 64 + wid * 16 + lr) * 3072 + lcs;
    const uint16_t* sB = Kb + (size_t)(jtB * 64 + wid * 16 + lr) * 3072 + lcs;
    gld16(sA, Ka + wid * 16 * 64);
    gld16(sA + (size_t)8 * 3072, Ka + (wid * 16 + 8) * 64);
    gld16(sB, Kb2 + wid * 16 * 64);
    gld16(sB + (size_t)8 * 3072, Kb2 + (wid * 16 + 8) * 64);
  }
  int it0 = jtA + ph;
  v4f cpA[2] = {vzero(), vzero()}, cpB[2] = {vzero(), vzero()};
  for (int it = it0; it < 16; it += 2){
    __syncthreads();                          // prev reads of Qs done
    {
      const uint16_t* sQ = Qb + (size_t)(it * 64 + wid * 16 + lr) * 3072 + lcs;
      gld16(sQ, Qs + wid * 16 * 64);
      gld16(sQ + (size_t)8 * 3072, Qs + (wid * 16 + 8) * 64);
    }
    __syncthreads();                          // Qs (and first-iter K) ready
    bool doB = (it >= jtB);
    v4f sa[2][2], sb[2][2];
    #pragma unroll
    for (int a = 0; a < 2; ++a)
      #pragma unroll
      for (int c = 0; c < 2; ++c){ sa[a][c] = vzero(); sb[a][c] = vzero(); }
    #pragma unroll
    for (int kc = 0; kc < 2; ++kc){
      int cs = ((kc * 4 + lg) ^ sw) * 8;
      v8bf aq[2], k1[2], k2[2];
      #pragma unroll
      for (int ni = 0; ni < 2; ++ni)
        aq[ni] = *(const v8bf*)(Qs + (wc * 32 + ni * 16 + l15) * 64 + cs);
      #pragma unroll
      for (int mj = 0; mj < 2; ++mj)
        k1[mj] = *(const v8bf*)(Ka + (wr * 32 + mj * 16 + l15) * 64 + cs);
      __builtin_amdgcn_s_setprio(1);
      #pragma unroll
      for (int mj = 0; mj < 2; ++mj)
        #pragma unroll
        for (int ni = 0; ni < 2; ++ni)
          sa[mj][ni] = __builtin_amdgcn_mfma_f32_16x16x32_bf16(k1[mj], aq[ni], sa[mj][ni], 0, 0, 0);
      __builtin_amdgcn_s_setprio(0);
      if (doB){
        #pragma unroll
        for (int mj = 0; mj < 2; ++mj)
          k2[mj] = *(const v8bf*)(Kb2 + (wr * 32 + mj * 16 + l15) * 64 + cs);
        __builtin_amdgcn_s_setprio(1);
        #pragma unroll
        for (int mj = 0; mj < 2; ++mj)
          #pragma unroll
          for (int ni = 0; ni < 2; ++ni)
            sb[mj][ni] = __builtin_amdgcn_mfma_f32_16x16x32_bf16(k2[mj], aq[ni], sb[mj][ni], 0, 0, 0);
        __builtin_amdgcn_s_setprio(0);
      }
    }
    bool diagA = (it == jtA), diagB = (it == jtB);
    int tri = it * (it + 1) / 2;
    uint16_t* dA = Pbh + (size_t)(tri + jtA) * 4096;
    uint16_t* dB = Pbh + (size_t)(tri + jtB) * 4096;
    #pragma unroll
    for (int mj = 0; mj < 2; ++mj)
      #pragma unroll
      for (int ni = 0; ni < 2; ++ni){
        int iL = wc * 32 + ni * 16 + l15;
        int jb = wr * 32 + mj * 16 + lg * 4;
        int off = iL * 64 + (((jb >> 3) ^ (iL & 7)) * 8) + (jb & 7);
        {
          float e0 = (!diagA || jb + 0 <= iL) ? __expf(sa[mj][ni][0] * 0.03125f) : 0.f;
          float e1 = (!diagA || jb + 1 <= iL) ? __expf(sa[mj][ni][1] * 0.03125f) : 0.f;
          float e2 = (!diagA || jb + 2 <= iL) ? __expf(sa[mj][ni][2] * 0.03125f) : 0.f;
          float e3 = (!diagA || jb + 3 <= iL) ? __expf(sa[mj][ni][3] * 0.03125f) : 0.f;
          v4f e4 = {e0, e1, e2, e3};
          cpA[mj] += e4;
          uint2 pk;
          pk.x = (uint32_t)f2bf(e0) | ((uint32_t)f2bf(e1) << 16);
          pk.y = (uint32_t)f2bf(e2) | ((uint32_t)f2bf(e3) << 16);
          *(uint2*)(dA + off) = pk;
        }
        if (doB){
          float e0 = (!diagB || jb + 0 <= iL) ? __expf(sb[mj][ni][0] * 0.03125f) : 0.f;
          float e1 = (!diagB || jb + 1 <= iL) ? __expf(sb[mj][ni][1] * 0.03125f) : 0.f;
          float e2 = (!diagB || jb + 2 <= iL) ? __expf(sb[mj][ni][2] * 0.03125f) : 0.f;
          float e3 = (!diagB || jb + 3 <= iL) ? __expf(sb[mj][ni][3] * 0.03125f) : 0.f;
          v4f e4 = {e0, e1, e2, e3};
          cpB[mj] += e4;
          uint2 pk;
          pk.x = (uint32_t)f2bf(e0) | ((uint32_t)f2bf(e1) << 16);
          pk.y = (uint32_t)f2bf(e2) | ((uint32_t)f2bf(e3) << 16);
          *(uint2*)(dB + off) = pk;
        }
      }
  }
  // csum: reduce over i (l15 lanes), then atomicAdd per j
  #pragma unroll
  for (int mj = 0; mj < 2; ++mj)
    #pragma unroll
    for (int m = 1; m <= 8; m <<= 1)
      #pragma unroll
      for (int r = 0; r < 4; ++r){
        cpA[mj][r] += __shfl_xor(cpA[mj][r], m, 64);
        cpB[mj][r] += __shfl_xor(cpB[mj][r], m, 64);
      }
  if (l15 == 0){
    #pragma unroll
    for (int mj = 0; mj < 2; ++mj)
      #pragma unroll
      for (int r = 0; r < 4; ++r){
        int jo = wr * 32 + mj * 16 + lg * 4 + r;
        atomicAdd(&csum[(size_t)bh * 1024 + jtA * 64 + jo], cpA[mj][r]);
        atomicAdd(&csum[(size_t)bh * 1024 + jtB * 64 + jo], cpB[mj][r]);
      }
  }
}

// ---------------- V' = V * mask/colsum, transposed + chunk-swizzled [bh][64 d][1024 j] ----------------
__global__ __launch_bounds__(256)
void k_vprep(const uint16_t* __restrict__ QKVg, const float* __restrict__ csum,
             const float* __restrict__ mask, uint16_t* __restrict__ Vp){
  __shared__ __align__(16) uint16_t Vs[128 * 72];
  __shared__ float scb[128];
  int tid = threadIdx.x;
  int bid = blockIdx.x, xcd = bid & 7, idx = bid >> 3;
  int bh = xcd * 8 + (idx & 7);
  int jt = idx >> 3;
  int b = bh >> 4, h = bh & 15;
  int j0 = jt * 128;
  stage64(Vs,           QKVg + ((size_t)(b * 1024 + j0)) * 3072 + 2048 + h * 64, 3072, tid);
  stage64(Vs + 64 * 72, QKVg + ((size_t)(b * 1024 + j0 + 64)) * 3072 + 2048 + h * 64, 3072, tid);
  if (tid < 128) scb[tid] = mask[b * 1024 + j0 + tid] / csum[(size_t)bh * 1024 + j0 + tid];
  __syncthreads();
  int d = tid >> 2, jc = (tid & 3) * 32;
  #pragma unroll
  for (int g8 = 0; g8 < 4; ++g8){
    union { uint16_t h[8]; uint4 v; } o;
    #pragma unroll
    for (int e = 0; e < 8; ++e){
      int j = jc + g8 * 8 + e;
      o.h[e] = f2bf(bf2f(Vs[j * 72 + d]) * scb[j]);
    }
    int jl = jc + g8 * 8;
    int wbase = jl & ~63;
    int c = (jl & 63) >> 3;
    int jphys = wbase + ((c ^ (d & 7)) * 8);
    *(uint4*)(Vp + (size_t)bh * 65536 + (size_t)d * 1024 + j0 + jphys) = o.v;
  }
}

// ---------------- k_pv: O = P @ V' — barrier-free streaming loop, direct reg loads ----------------
// grid 1024 = (xcd, slot, it). Wave w owns O rows [w*16, w*16+16); P rows are wave-exclusive.
__global__ __launch_bounds__(256, 4)
void k_pv(const uint16_t* __restrict__ Pws, const uint16_t* __restrict__ Vp,
          float* __restrict__ out){
  __shared__ __align__(16) float Of[64 * 68];  // epilogue only
  int tid = threadIdx.x, lane = tid & 63, l15 = lane & 15, lg = lane >> 4, wid = tid >> 6;
  int sw = l15 & 7;
  int bid = blockIdx.x, xcd = bid & 7, idx = bid >> 3;
  int bh = xcd * 8 + (idx & 7);
  int it = idx >> 3;
  int b = bh >> 4, h = bh & 15;
  const uint16_t* Pbh = Pws + (size_t)bh * 557056 + (size_t)(it * (it + 1) / 2) * 4096
                      + (wid * 16 + l15) * 64;
  const uint16_t* Vb  = Vp + (size_t)bh * 65536;
  v4f oacc[4];
  #pragma unroll
  for (int c = 0; c < 4; ++c) oacc[c] = vzero();

  #pragma unroll 2
  for (int jt = 0; jt <= it; ++jt){
    const uint16_t* pt = Pbh + (size_t)jt * 4096;
    const uint16_t* vt = Vb + jt * 64;
    #pragma unroll
    for (int kc = 0; kc < 2; ++kc){
      int cs = ((kc * 4 + lg) ^ sw) * 8;
      v8bf pa = *(const v8bf*)(pt + cs);
      v8bf vb_[4];
      #pragma unroll
      for (int dj = 0; dj < 4; ++dj)
        vb_[dj] = *(const v8bf*)(vt + (size_t)(dj * 16 + l15) * 1024 + cs);
      __builtin_amdgcn_s_setprio(1);
      #pragma unroll
      for (int dj = 0; dj < 4; ++dj)
        oacc[dj] = __builtin_amdgcn_mfma_f32_16x16x32_bf16(pa, vb_[dj], oacc[dj], 0, 0, 0);
      __builtin_amdgcn_s_setprio(0);
    }
  }
  // epilogue: LDS-staged coalesced f32 store
  #pragma unroll
  for (int dj = 0; dj < 4; ++dj)
    #pragma unroll
    for (int r = 0; r < 4; ++r)
      Of[(wid * 16 + lg * 4 + r) * 68 + dj * 16 + l15] = oacc[dj][r];
  __syncthreads();
  {
    int row = tid >> 2, c0 = (tid & 3) * 16;
    float* gp = out + ((size_t)(b * 1024) + it * 64 + row) * 1024 + h * 64 + c0;
    const float* sp = Of + row * 68 + c0;
    #pragma unroll
    for (int c = 0; c < 4; ++c)
      *(float4*)(gp + c * 4) = *(const float4*)(sp + c * 4);
  }
}

extern "C" void kernel_launch(void* const* d_in, const int* in_sizes, int n_in,
                              void* d_out, int out_size, void* d_ws, size_t ws_size,
                              hipStream_t stream) {
  (void)in_sizes; (void)n_in; (void)out_size; (void)ws_size;
  const float* X    = (const float*)d_in[0];
  const float* mask = (const float*)d_in[1];
  const float* Wq   = (const float*)d_in[2];
  const float* bq   = (const float*)d_in[3];
  const float* Wk   = (const float*)d_in[4];
  const float* bk   = (const float*)d_in[5];
  const float* Wv   = (const float*)d_in[6];
  const float* bv   = (const float*)d_in[7];
  const float* Aq   = (const float*)d_in[8];
  const float* Bq   = (const float*)d_in[9];
  const float* Ak   = (const float*)d_in[10];
  const float* Bk   = (const float*)d_in[11];
  const float* Av   = (const float*)d_in[12];
  const float* Bv   = (const float*)d_in[13];
  float* out = (float*)d_out;

  uint16_t* Xb   = (uint16_t*)d_ws;                        // 8 MB
  uint16_t* Weff = Xb + (size_t)4096 * 1024;               // 6 MB
  uint16_t* QKV  = Weff + (size_t)3 * 1024 * 1024;         // 24 MB
  uint16_t* Vp   = QKV + (size_t)4096 * 3072;              // 8 MB
  float*    csum = (float*)(Vp + (size_t)64 * 64 * 1024);  // 256 KB
  uint16_t* Pws  = (uint16_t*)((char*)d_ws + 48496640ULL); // 68 MB P tiles

  k_xcast<<<2048, 256, 0, stream>>>(X, Xb, csum);
  k_weff<<<dim3(4096, 3), 256, 0, stream>>>(Wq, Aq, Bq, Wk, Ak, Bk, Wv, Av, Bv, Weff);
  k_gemm<<<768, 256, 0, stream>>>(Xb, Weff, bq, bk, bv, QKV);
  k_score<<<1024, 256, 0, stream>>>(QKV, csum, Pws);
  k_vprep<<<512, 256, 0, stream>>>(QKV, csum, mask, Vp);
  k_pv<<<1024, 256, 0, stream>>>(Pws, Vp, out);
}

// Round 12
// 100.916 us; speedup vs baseline: 1.1051x; 1.1051x over previous
//
#include <hip/hip_runtime.h>
#include <stdint.h>

typedef __bf16 v8bf __attribute__((ext_vector_type(8)));
typedef float  v4f  __attribute__((ext_vector_type(4)));

__device__ __forceinline__ uint16_t f2bf(float f){
  union { float f; uint32_t u; } v; v.f = f;
  uint32_t r = v.u + 0x7FFFu + ((v.u >> 16) & 1u);
  return (uint16_t)(r >> 16);
}
__device__ __forceinline__ float bf2f(uint16_t u){
  union { uint32_t u; float f; } v; v.u = ((uint32_t)u) << 16; return v.f;
}
__device__ __forceinline__ v4f vzero(){ v4f z = {0.f,0.f,0.f,0.f}; return z; }

// async global->LDS, 16B per lane; LDS dest is wave-uniform base + lane*16
__device__ __forceinline__ void gld16(const uint16_t* __restrict__ g, uint16_t* l){
  __builtin_amdgcn_global_load_lds((const __attribute__((address_space(1))) void*)g,
                                   (__attribute__((address_space(3))) void*)l, 16, 0, 0);
}

// ---- 64x64 bf16 tile staging, LDS row stride 72 (vprep) ----
__device__ __forceinline__ void ld64(uint4 r[2], const uint16_t* __restrict__ g, int ldg, int tid){
  int row = tid >> 2, c = (tid & 3) * 16;
  r[0] = *(const uint4*)(g + (size_t)row * ldg + c);
  r[1] = *(const uint4*)(g + (size_t)row * ldg + c + 8);
}
__device__ __forceinline__ void st64(uint16_t* __restrict__ s, const uint4 r[2], int tid){
  int row = tid >> 2, c = (tid & 3) * 16;
  *(uint4*)(s + row * 72 + c) = r[0];
  *(uint4*)(s + row * 72 + c + 8) = r[1];
}
__device__ __forceinline__ void stage64(uint16_t* s, const uint16_t* g, int ldg, int tid){
  uint4 r[2]; ld64(r, g, ldg, tid); st64(s, r, tid);
}

// ---------------- fused prep: xcast + csum zero + weff ----------------
__global__ void k_prep(const float* __restrict__ X, uint16_t* __restrict__ Xb,
                       float* __restrict__ csum,
                       const float* __restrict__ Wq, const float* __restrict__ Aq, const float* __restrict__ Bq,
                       const float* __restrict__ Wk, const float* __restrict__ Ak, const float* __restrict__ Bk,
                       const float* __restrict__ Wv, const float* __restrict__ Av, const float* __restrict__ Bv,
                       uint16_t* __restrict__ Wo){
  int bid = blockIdx.x, tid = threadIdx.x;
  if (bid < 2048){
    int i = (bid * 256 + tid) * 8;
    float4 a = *(const float4*)(X + i);
    float4 b = *(const float4*)(X + i + 4);
    union { uint16_t h[8]; uint4 v; } o;
    o.h[0]=f2bf(a.x); o.h[1]=f2bf(a.y); o.h[2]=f2bf(a.z); o.h[3]=f2bf(a.w);
    o.h[4]=f2bf(b.x); o.h[5]=f2bf(b.y); o.h[6]=f2bf(b.z); o.h[7]=f2bf(b.w);
    *(uint4*)(Xb + i) = o.v;
    if (bid < 64)                       // zero csum (64*1024 f32 = 16384 float4)
      ((float4*)csum)[bid * 256 + tid] = make_float4(0.f, 0.f, 0.f, 0.f);
  } else {
    int w = bid - 2048;
    int y = w >> 12;
    const float* W  = (y == 0) ? Wq : (y == 1) ? Wk : Wv;
    const float* A  = (y == 0) ? Aq : (y == 1) ? Ak : Av;
    const float* Bm = (y == 0) ? Bq : (y == 1) ? Bk : Bv;
    int idx = (w & 4095) * 256 + tid;
    int f = idx >> 10, k = idx & 1023;
    float acc = W[idx];
    #pragma unroll
    for (int r = 0; r < 16; ++r) acc += Bm[f * 16 + r] * A[r * 1024 + k];
    Wo[(size_t)y * 1048576 + idx] = f2bf(acc);
  }
}

// ---------------- fused QKV projection GEMM (m97 structure + XOR swizzle) ----------------
__global__ __launch_bounds__(256, 4)
void k_gemm(const uint16_t* __restrict__ Ag, const uint16_t* __restrict__ Bg,
            const float* __restrict__ qb, const float* __restrict__ kb,
            const float* __restrict__ vb, uint16_t* __restrict__ Cg){
  __shared__ __align__(16) uint16_t smem[16896];
  uint16_t* As = smem;
  uint16_t* Bs = smem + 8192;
  int tid = threadIdx.x, lane = tid & 63, wid = tid >> 6;
  int l15 = lane & 15, lg = lane >> 4;
  int wr = wid >> 1, wc = wid & 1;
  int bid = blockIdx.x, xcd = bid & 7, idx = bid >> 3;
  int nb = xcd * 96 + idx;
  int mt = nb / 24, nt = nb - mt * 24;
  int m0 = mt * 128, n0 = nt * 128;

  int lr  = lane >> 3;
  int lcs = (((lane & 7) ^ lr)) * 8;
  const uint16_t* Abase = Ag + (size_t)(m0 + wid * 32 + lr) * 1024 + lcs;
  const uint16_t* Bbase = Bg + (size_t)(n0 + wid * 32 + lr) * 1024 + lcs;
  uint16_t* Alds = As + wid * 32 * 64;
  uint16_t* Blds = Bs + wid * 32 * 64;

  int sw = l15 & 7;

  v4f acc[4][4];
  #pragma unroll
  for (int a = 0; a < 4; ++a)
    #pragma unroll
    for (int c = 0; c < 4; ++c) acc[a][c] = vzero();

  for (int kk = 0; kk < 1024; kk += 64){
    __syncthreads();
    #pragma unroll
    for (int i = 0; i < 4; ++i){
      gld16(Abase + (size_t)(i * 8) * 1024 + kk, Alds + i * 8 * 64);
      gld16(Bbase + (size_t)(i * 8) * 1024 + kk, Blds + i * 8 * 64);
    }
    __syncthreads();
    #pragma unroll
    for (int kc = 0; kc < 2; ++kc){
      v8bf af[4], bfr[4];
      int cs = ((kc * 4 + lg) ^ sw) * 8;
      #pragma unroll
      for (int mi = 0; mi < 4; ++mi)
        af[mi] = *(const v8bf*)(As + (wr * 64 + mi * 16 + l15) * 64 + cs);
      #pragma unroll
      for (int nj = 0; nj < 4; ++nj)
        bfr[nj] = *(const v8bf*)(Bs + (wc * 64 + nj * 16 + l15) * 64 + cs);
      #pragma unroll
      for (int mi = 0; mi < 4; ++mi)
        #pragma unroll
        for (int nj = 0; nj < 4; ++nj)
          acc[mi][nj] = __builtin_amdgcn_mfma_f32_16x16x32_bf16(af[mi], bfr[nj], acc[mi][nj], 0, 0, 0);
    }
  }
  __syncthreads();
  uint16_t* Ct = smem;
  #pragma unroll
  for (int nj = 0; nj < 4; ++nj){
    int n = n0 + wc * 64 + nj * 16 + l15;
    float bv_ = (n < 1024) ? qb[n] : (n < 2048) ? kb[n - 1024] : vb[n - 2048];
    #pragma unroll
    for (int mi = 0; mi < 4; ++mi)
      #pragma unroll
      for (int r = 0; r < 4; ++r){
        int ml = wr * 64 + mi * 16 + lg * 4 + r;
        Ct[ml * 132 + wc * 64 + nj * 16 + l15] = f2bf(acc[mi][nj][r] + bv_);
      }
  }
  __syncthreads();
  {
    int row = tid >> 1;
    int c0  = (tid & 1) * 64;
    uint16_t* gp = Cg + (size_t)(m0 + row) * 3072 + n0 + c0;
    const uint16_t* sp = Ct + row * 132 + c0;
    #pragma unroll
    for (int c = 0; c < 8; ++c)
      *(uint4*)(gp + c * 8) = *(const uint4*)(sp + c * 8);
  }
}

// ---------------- k_score: compute S-tiles once; exp; csum; LDS-staged P dump ----------------
// grid 1024 = (xcd, slot, pr, ph). A=K (rows j), B=Q (rows i): frag col(l15)=i, row(lg*4+r)=j.
// P tile layout in ws: elem (i, j) at i*64 + ((j>>3)^(i&7))*8 + (j&7)  (chunk-XOR swizzled).
__global__ __launch_bounds__(256, 4)
void k_score(const uint16_t* __restrict__ QKVg, float* __restrict__ csum,
             uint16_t* __restrict__ Pws){
  __shared__ __align__(16) uint16_t Ka[4096], Kb2[4096], Qs[4096], PsA[4096], PsB[4096];
  int tid = threadIdx.x, lane = tid & 63, wid = tid >> 6;
  int l15 = lane & 15, lg = lane >> 4;
  int wr = wid >> 1, wc = wid & 1;
  int sw = l15 & 7;
  int bid = blockIdx.x, xcd = bid & 7, idx = bid >> 3;
  int bh = xcd * 8 + (idx & 7);
  int rest = idx >> 3;
  int pr = rest & 7, ph = rest >> 3;
  int b = bh >> 4, h = bh & 15;
  int jtA = pr, jtB = 15 - pr;
  const uint16_t* Qb = QKVg + (size_t)b * 1024 * 3072 + h * 64;
  const uint16_t* Kb = QKVg + (size_t)b * 1024 * 3072 + 1024 + h * 64;
  uint16_t* Pbh = Pws + (size_t)bh * 557056;

  int lr  = lane >> 3;
  int lcs = ((lane & 7) ^ lr) * 8;           // pre-swizzled source chunk
  {                                           // stage K tiles once (swizzled image, gld16)
    const uint16_t* sA = Kb + (size_t)(jtA * 64 + wid * 16 + lr) * 3072 + lcs;
    const uint16_t* sB = Kb + (size_t)(jtB * 64 + wid * 16 + lr) * 3072 + lcs;
    gld16(sA, Ka + wid * 16 * 64);
    gld16(sA + (size_t)8 * 3072, Ka + (wid * 16 + 8) * 64);
    gld16(sB, Kb2 + wid * 16 * 64);
    gld16(sB + (size_t)8 * 3072, Kb2 + (wid * 16 + 8) * 64);
  }
  int it0 = jtA + ph;
  v4f cpA[2] = {vzero(), vzero()}, cpB[2] = {vzero(), vzero()};
  for (int it = it0; it < 16; it += 2){
    __syncthreads();                          // prev dumps done / Qs free
    {
      const uint16_t* sQ = Qb + (size_t)(it * 64 + wid * 16 + lr) * 3072 + lcs;
      gld16(sQ, Qs + wid * 16 * 64);
      gld16(sQ + (size_t)8 * 3072, Qs + (wid * 16 + 8) * 64);
    }
    __syncthreads();                          // Qs (and first-iter K) ready
    bool doB = (it >= jtB);
    v4f sa[2][2], sb[2][2];
    #pragma unroll
    for (int a = 0; a < 2; ++a)
      #pragma unroll
      for (int c = 0; c < 2; ++c){ sa[a][c] = vzero(); sb[a][c] = vzero(); }
    #pragma unroll
    for (int kc = 0; kc < 2; ++kc){
      int cs = ((kc * 4 + lg) ^ sw) * 8;
      v8bf aq[2], k1[2], k2[2];
      #pragma unroll
      for (int ni = 0; ni < 2; ++ni)
        aq[ni] = *(const v8bf*)(Qs + (wc * 32 + ni * 16 + l15) * 64 + cs);
      #pragma unroll
      for (int mj = 0; mj < 2; ++mj)
        k1[mj] = *(const v8bf*)(Ka + (wr * 32 + mj * 16 + l15) * 64 + cs);
      __builtin_amdgcn_s_setprio(1);
      #pragma unroll
      for (int mj = 0; mj < 2; ++mj)
        #pragma unroll
        for (int ni = 0; ni < 2; ++ni)
          sa[mj][ni] = __builtin_amdgcn_mfma_f32_16x16x32_bf16(k1[mj], aq[ni], sa[mj][ni], 0, 0, 0);
      __builtin_amdgcn_s_setprio(0);
      if (doB){
        #pragma unroll
        for (int mj = 0; mj < 2; ++mj)
          k2[mj] = *(const v8bf*)(Kb2 + (wr * 32 + mj * 16 + l15) * 64 + cs);
        __builtin_amdgcn_s_setprio(1);
        #pragma unroll
        for (int mj = 0; mj < 2; ++mj)
          #pragma unroll
          for (int ni = 0; ni < 2; ++ni)
            sb[mj][ni] = __builtin_amdgcn_mfma_f32_16x16x32_bf16(k2[mj], aq[ni], sb[mj][ni], 0, 0, 0);
        __builtin_amdgcn_s_setprio(0);
      }
    }
    bool diagA = (it == jtA), diagB = (it == jtB);
    #pragma unroll
    for (int mj = 0; mj < 2; ++mj)
      #pragma unroll
      for (int ni = 0; ni < 2; ++ni){
        int iL = wc * 32 + ni * 16 + l15;
        int jb = wr * 32 + mj * 16 + lg * 4;
        int off = iL * 64 + (((jb >> 3) ^ (iL & 7)) * 8) + (jb & 7);
        {
          float e0 = (!diagA || jb + 0 <= iL) ? __expf(sa[mj][ni][0] * 0.03125f) : 0.f;
          float e1 = (!diagA || jb + 1 <= iL) ? __expf(sa[mj][ni][1] * 0.03125f) : 0.f;
          float e2 = (!diagA || jb + 2 <= iL) ? __expf(sa[mj][ni][2] * 0.03125f) : 0.f;
          float e3 = (!diagA || jb + 3 <= iL) ? __expf(sa[mj][ni][3] * 0.03125f) : 0.f;
          v4f e4 = {e0, e1, e2, e3};
          cpA[mj] += e4;
          uint2 pk;
          pk.x = (uint32_t)f2bf(e0) | ((uint32_t)f2bf(e1) << 16);
          pk.y = (uint32_t)f2bf(e2) | ((uint32_t)f2bf(e3) << 16);
          *(uint2*)(PsA + off) = pk;
        }
        if (doB){
          float e0 = (!diagB || jb + 0 <= iL) ? __expf(sb[mj][ni][0] * 0.03125f) : 0.f;
          float e1 = (!diagB || jb + 1 <= iL) ? __expf(sb[mj][ni][1] * 0.03125f) : 0.f;
          float e2 = (!diagB || jb + 2 <= iL) ? __expf(sb[mj][ni][2] * 0.03125f) : 0.f;
          float e3 = (!diagB || jb + 3 <= iL) ? __expf(sb[mj][ni][3] * 0.03125f) : 0.f;
          v4f e4 = {e0, e1, e2, e3};
          cpB[mj] += e4;
          uint2 pk;
          pk.x = (uint32_t)f2bf(e0) | ((uint32_t)f2bf(e1) << 16);
          pk.y = (uint32_t)f2bf(e2) | ((uint32_t)f2bf(e3) << 16);
          *(uint2*)(PsB + off) = pk;
        }
      }
    __syncthreads();                          // Ps visible
    {
      int tri = it * (it + 1) / 2;
      uint16_t* dA = Pbh + (size_t)(tri + jtA) * 4096 + tid * 16;
      uint4 a0 = *(const uint4*)(PsA + tid * 16);
      uint4 a1 = *(const uint4*)(PsA + tid * 16 + 8);
      *(uint4*)dA = a0; *(uint4*)(dA + 8) = a1;
      if (doB){
        uint16_t* dB = Pbh + (size_t)(tri + jtB) * 4096 + tid * 16;
        uint4 b0 = *(const uint4*)(PsB + tid * 16);
        uint4 b1 = *(const uint4*)(PsB + tid * 16 + 8);
        *(uint4*)dB = b0; *(uint4*)(dB + 8) = b1;
      }
    }
  }
  // csum: reduce over i (l15 lanes), then atomicAdd per j
  #pragma unroll
  for (int mj = 0; mj < 2; ++mj)
    #pragma unroll
    for (int m = 1; m <= 8; m <<= 1)
      #pragma unroll
      for (int r = 0; r < 4; ++r){
        cpA[mj][r] += __shfl_xor(cpA[mj][r], m, 64);
        cpB[mj][r] += __shfl_xor(cpB[mj][r], m, 64);
      }
  if (l15 == 0){
    #pragma unroll
    for (int mj = 0; mj < 2; ++mj)
      #pragma unroll
      for (int r = 0; r < 4; ++r){
        int jo = wr * 32 + mj * 16 + lg * 4 + r;
        atomicAdd(&csum[(size_t)bh * 1024 + jtA * 64 + jo], cpA[mj][r]);
        atomicAdd(&csum[(size_t)bh * 1024 + jtB * 64 + jo], cpB[mj][r]);
      }
  }
}

// ---------------- V' = V * mask/colsum, transposed + chunk-swizzled [bh][64 d][1024 j] ----------------
__global__ __launch_bounds__(256)
void k_vprep(const uint16_t* __restrict__ QKVg, const float* __restrict__ csum,
             const float* __restrict__ mask, uint16_t* __restrict__ Vp){
  __shared__ __align__(16) uint16_t Vs[128 * 72];
  __shared__ float scb[128];
  int tid = threadIdx.x;
  int bid = blockIdx.x, xcd = bid & 7, idx = bid >> 3;
  int bh = xcd * 8 + (idx & 7);
  int jt = idx >> 3;
  int b = bh >> 4, h = bh & 15;
  int j0 = jt * 128;
  stage64(Vs,           QKVg + ((size_t)(b * 1024 + j0)) * 3072 + 2048 + h * 64, 3072, tid);
  stage64(Vs + 64 * 72, QKVg + ((size_t)(b * 1024 + j0 + 64)) * 3072 + 2048 + h * 64, 3072, tid);
  if (tid < 128) scb[tid] = mask[b * 1024 + j0 + tid] / csum[(size_t)bh * 1024 + j0 + tid];
  __syncthreads();
  int d = tid >> 2, jc = (tid & 3) * 32;
  #pragma unroll
  for (int g8 = 0; g8 < 4; ++g8){
    union { uint16_t h[8]; uint4 v; } o;
    #pragma unroll
    for (int e = 0; e < 8; ++e){
      int j = jc + g8 * 8 + e;
      o.h[e] = f2bf(bf2f(Vs[j * 72 + d]) * scb[j]);
    }
    int jl = jc + g8 * 8;
    int wbase = jl & ~63;
    int c = (jl & 63) >> 3;
    int jphys = wbase + ((c ^ (d & 7)) * 8);
    *(uint4*)(Vp + (size_t)bh * 65536 + (size_t)d * 1024 + j0 + jphys) = o.v;
  }
}

// ---------------- k_pv: O = P @ V' — double-buffered gld16 staging, 1 barrier/tile ----------------
// grid 1024 = (xcd, slot, it). Wave w computes O rows [w*16, w*16+16).
__global__ __launch_bounds__(256, 4)
void k_pv(const uint16_t* __restrict__ Pws, const uint16_t* __restrict__ Vp,
          float* __restrict__ out){
  __shared__ __align__(16) uint16_t smem[16384];   // 2 bufs x (Pt 4096 | Vt 4096); Of f32 alias
  int tid = threadIdx.x, lane = tid & 63, l15 = lane & 15, lg = lane >> 4, wid = tid >> 6;
  int sw = l15 & 7;
  int bid = blockIdx.x, xcd = bid & 7, idx = bid >> 3;
  int bh = xcd * 8 + (idx & 7);
  int it = idx >> 3;
  int b = bh >> 4, h = bh & 15;
  const uint16_t* Pbh = Pws + (size_t)bh * 557056 + (size_t)(it * (it + 1) / 2) * 4096;
  const uint16_t* Vb  = Vp + (size_t)bh * 65536;
  v4f oacc[4];
  #pragma unroll
  for (int c = 0; c < 4; ++c) oacc[c] = vzero();

  // STAGE jt into buffer buf (4 gld16/thread: 2 P + 2 V)
  #define PV_STAGE(buf, jt) do {                                                        \
    uint16_t* Pt_ = smem + (buf) * 8192;                                                \
    uint16_t* Vt_ = Pt_ + 4096;                                                         \
    const uint16_t* ps = Pbh + (size_t)(jt) * 4096;                                     \
    gld16(ps + wid * 512 + lane * 8,        Pt_ + wid * 512);                           \
    gld16(ps + 2048 + wid * 512 + lane * 8, Pt_ + 2048 + wid * 512);                    \
    const uint16_t* vs = Vb + (size_t)(jt) * 64;                                        \
    gld16(vs + (size_t)(wid * 8 + (lane >> 3)) * 1024 + (lane & 7) * 8,      Vt_ + wid * 512); \
    gld16(vs + (size_t)(32 + wid * 8 + (lane >> 3)) * 1024 + (lane & 7) * 8, Vt_ + 2048 + wid * 512); \
  } while (0)

  PV_STAGE(0, 0);
  __syncthreads();                             // buf0 complete (barrier drains vmcnt)
  int cur = 0;
  for (int jt = 0; jt <= it; ++jt){
    if (jt < it) PV_STAGE(cur ^ 1, jt + 1);    // issue next tile early (hidden under compute)
    const uint16_t* Pt = smem + cur * 8192;
    const uint16_t* Vt = Pt + 4096;
    #pragma unroll
    for (int kc = 0; kc < 2; ++kc){
      int cs = ((kc * 4 + lg) ^ sw) * 8;
      v8bf pa = *(const v8bf*)(Pt + (wid * 16 + l15) * 64 + cs);
      v8bf vb_[4];
      #pragma unroll
      for (int dj = 0; dj < 4; ++dj)
        vb_[dj] = *(const v8bf*)(Vt + (dj * 16 + l15) * 64 + cs);
      __builtin_amdgcn_s_setprio(1);
      #pragma unroll
      for (int dj = 0; dj < 4; ++dj)
        oacc[dj] = __builtin_amdgcn_mfma_f32_16x16x32_bf16(pa, vb_[dj], oacc[dj], 0, 0, 0);
      __builtin_amdgcn_s_setprio(0);
    }
    __syncthreads();                           // next-tile loads complete; cur free to overwrite
    cur ^= 1;
  }
  #undef PV_STAGE
  // epilogue: LDS-staged coalesced f32 store
  float* Of = (float*)smem;                    // 64 x 68 f32 = 17408 B
  #pragma unroll
  for (int dj = 0; dj < 4; ++dj)
    #pragma unroll
    for (int r = 0; r < 4; ++r)
      Of[(wid * 16 + lg * 4 + r) * 68 + dj * 16 + l15] = oacc[dj][r];
  __syncthreads();
  {
    int row = tid >> 2, c0 = (tid & 3) * 16;
    float* gp = out + ((size_t)(b * 1024) + it * 64 + row) * 1024 + h * 64 + c0;
    const float* sp = Of + row * 68 + c0;
    #pragma unroll
    for (int c = 0; c < 4; ++c)
      *(float4*)(gp + c * 4) = *(const float4*)(sp + c * 4);
  }
}

extern "C" void kernel_launch(void* const* d_in, const int* in_sizes, int n_in,
                              void* d_out, int out_size, void* d_ws, size_t ws_size,
                              hipStream_t stream) {
  (void)in_sizes; (void)n_in; (void)out_size; (void)ws_size;
  const float* X    = (const float*)d_in[0];
  const float* mask = (const float*)d_in[1];
  const float* Wq   = (const float*)d_in[2];
  const float* bq   = (const float*)d_in[3];
  const float* Wk   = (const float*)d_in[4];
  const float* bk   = (const float*)d_in[5];
  const float* Wv   = (const float*)d_in[6];
  const float* bv   = (const float*)d_in[7];
  const float* Aq   = (const float*)d_in[8];
  const float* Bq   = (const float*)d_in[9];
  const float* Ak   = (const float*)d_in[10];
  const float* Bk   = (const float*)d_in[11];
  const float* Av   = (const float*)d_in[12];
  const float* Bv   = (const float*)d_in[13];
  float* out = (float*)d_out;

  uint16_t* Xb   = (uint16_t*)d_ws;                        // 8 MB
  uint16_t* Weff = Xb + (size_t)4096 * 1024;               // 6 MB
  uint16_t* QKV  = Weff + (size_t)3 * 1024 * 1024;         // 24 MB
  uint16_t* Vp   = QKV + (size_t)4096 * 3072;              // 8 MB
  float*    csum = (float*)(Vp + (size_t)64 * 64 * 1024);  // 256 KB
  uint16_t* Pws  = (uint16_t*)((char*)d_ws + 48496640ULL); // 68 MB P tiles

  k_prep<<<14336, 256, 0, stream>>>(X, Xb, csum, Wq, Aq, Bq, Wk, Ak, Bk, Wv, Av, Bv, Weff);
  k_gemm<<<768, 256, 0, stream>>>(Xb, Weff, bq, bk, bv, QKV);
  k_score<<<1024, 256, 0, stream>>>(QKV, csum, Pws);
  k_vprep<<<512, 256, 0, stream>>>(QKV, csum, mask, Vp);
  k_pv<<<1024, 256, 0, stream>>>(Pws, Vp, out);
}

// Round 13
// 99.715 us; speedup vs baseline: 1.1185x; 1.0120x over previous
//
#include <hip/hip_runtime.h>
#include <stdint.h>

typedef __bf16 v8bf __attribute__((ext_vector_type(8)));
typedef float  v4f  __attribute__((ext_vector_type(4)));

__device__ __forceinline__ uint16_t f2bf(float f){
  union { float f; uint32_t u; } v; v.f = f;
  uint32_t r = v.u + 0x7FFFu + ((v.u >> 16) & 1u);
  return (uint16_t)(r >> 16);
}
__device__ __forceinline__ float bf2f(uint16_t u){
  union { uint32_t u; float f; } v; v.u = ((uint32_t)u) << 16; return v.f;
}
__device__ __forceinline__ v4f vzero(){ v4f z = {0.f,0.f,0.f,0.f}; return z; }

// async global->LDS, 16B per lane; LDS dest is wave-uniform base + lane*16
__device__ __forceinline__ void gld16(const uint16_t* __restrict__ g, uint16_t* l){
  __builtin_amdgcn_global_load_lds((const __attribute__((address_space(1))) void*)g,
                                   (__attribute__((address_space(3))) void*)l, 16, 0, 0);
}

// ---- 64x64 bf16 tile staging, LDS row stride 72 (vprep) ----
__device__ __forceinline__ void ld64(uint4 r[2], const uint16_t* __restrict__ g, int ldg, int tid){
  int row = tid >> 2, c = (tid & 3) * 16;
  r[0] = *(const uint4*)(g + (size_t)row * ldg + c);
  r[1] = *(const uint4*)(g + (size_t)row * ldg + c + 8);
}
__device__ __forceinline__ void st64(uint16_t* __restrict__ s, const uint4 r[2], int tid){
  int row = tid >> 2, c = (tid & 3) * 16;
  *(uint4*)(s + row * 72 + c) = r[0];
  *(uint4*)(s + row * 72 + c + 8) = r[1];
}
__device__ __forceinline__ void stage64(uint16_t* s, const uint16_t* g, int ldg, int tid){
  uint4 r[2]; ld64(r, g, ldg, tid); st64(s, r, tid);
}

// ---------------- fused prep: xcast + csum zero + weff ----------------
__global__ void k_prep(const float* __restrict__ X, uint16_t* __restrict__ Xb,
                       float* __restrict__ csum,
                       const float* __restrict__ Wq, const float* __restrict__ Aq, const float* __restrict__ Bq,
                       const float* __restrict__ Wk, const float* __restrict__ Ak, const float* __restrict__ Bk,
                       const float* __restrict__ Wv, const float* __restrict__ Av, const float* __restrict__ Bv,
                       uint16_t* __restrict__ Wo){
  int bid = blockIdx.x, tid = threadIdx.x;
  if (bid < 2048){
    int i = (bid * 256 + tid) * 8;
    float4 a = *(const float4*)(X + i);
    float4 b = *(const float4*)(X + i + 4);
    union { uint16_t h[8]; uint4 v; } o;
    o.h[0]=f2bf(a.x); o.h[1]=f2bf(a.y); o.h[2]=f2bf(a.z); o.h[3]=f2bf(a.w);
    o.h[4]=f2bf(b.x); o.h[5]=f2bf(b.y); o.h[6]=f2bf(b.z); o.h[7]=f2bf(b.w);
    *(uint4*)(Xb + i) = o.v;
    if (bid < 64)                       // zero csum (64*1024 f32 = 16384 float4)
      ((float4*)csum)[bid * 256 + tid] = make_float4(0.f, 0.f, 0.f, 0.f);
  } else {
    int w = bid - 2048;
    int y = w >> 12;
    const float* W  = (y == 0) ? Wq : (y == 1) ? Wk : Wv;
    const float* A  = (y == 0) ? Aq : (y == 1) ? Ak : Av;
    const float* Bm = (y == 0) ? Bq : (y == 1) ? Bk : Bv;
    int idx = (w & 4095) * 256 + tid;
    int f = idx >> 10, k = idx & 1023;
    float acc = W[idx];
    #pragma unroll
    for (int r = 0; r < 16; ++r) acc += Bm[f * 16 + r] * A[r * 1024 + k];
    Wo[(size_t)y * 1048576 + idx] = f2bf(acc);
  }
}

// ---------------- fused QKV projection GEMM (m97 structure + XOR swizzle) ----------------
__global__ __launch_bounds__(256, 4)
void k_gemm(const uint16_t* __restrict__ Ag, const uint16_t* __restrict__ Bg,
            const float* __restrict__ qb, const float* __restrict__ kb,
            const float* __restrict__ vb, uint16_t* __restrict__ Cg){
  __shared__ __align__(16) uint16_t smem[16896];
  uint16_t* As = smem;
  uint16_t* Bs = smem + 8192;
  int tid = threadIdx.x, lane = tid & 63, wid = tid >> 6;
  int l15 = lane & 15, lg = lane >> 4;
  int wr = wid >> 1, wc = wid & 1;
  int bid = blockIdx.x, xcd = bid & 7, idx = bid >> 3;
  int nb = xcd * 96 + idx;
  int mt = nb / 24, nt = nb - mt * 24;
  int m0 = mt * 128, n0 = nt * 128;

  int lr  = lane >> 3;
  int lcs = (((lane & 7) ^ lr)) * 8;
  const uint16_t* Abase = Ag + (size_t)(m0 + wid * 32 + lr) * 1024 + lcs;
  const uint16_t* Bbase = Bg + (size_t)(n0 + wid * 32 + lr) * 1024 + lcs;
  uint16_t* Alds = As + wid * 32 * 64;
  uint16_t* Blds = Bs + wid * 32 * 64;

  int sw = l15 & 7;

  v4f acc[4][4];
  #pragma unroll
  for (int a = 0; a < 4; ++a)
    #pragma unroll
    for (int c = 0; c < 4; ++c) acc[a][c] = vzero();

  for (int kk = 0; kk < 1024; kk += 64){
    __syncthreads();
    #pragma unroll
    for (int i = 0; i < 4; ++i){
      gld16(Abase + (size_t)(i * 8) * 1024 + kk, Alds + i * 8 * 64);
      gld16(Bbase + (size_t)(i * 8) * 1024 + kk, Blds + i * 8 * 64);
    }
    __syncthreads();
    #pragma unroll
    for (int kc = 0; kc < 2; ++kc){
      v8bf af[4], bfr[4];
      int cs = ((kc * 4 + lg) ^ sw) * 8;
      #pragma unroll
      for (int mi = 0; mi < 4; ++mi)
        af[mi] = *(const v8bf*)(As + (wr * 64 + mi * 16 + l15) * 64 + cs);
      #pragma unroll
      for (int nj = 0; nj < 4; ++nj)
        bfr[nj] = *(const v8bf*)(Bs + (wc * 64 + nj * 16 + l15) * 64 + cs);
      #pragma unroll
      for (int mi = 0; mi < 4; ++mi)
        #pragma unroll
        for (int nj = 0; nj < 4; ++nj)
          acc[mi][nj] = __builtin_amdgcn_mfma_f32_16x16x32_bf16(af[mi], bfr[nj], acc[mi][nj], 0, 0, 0);
    }
  }
  __syncthreads();
  uint16_t* Ct = smem;
  #pragma unroll
  for (int nj = 0; nj < 4; ++nj){
    int n = n0 + wc * 64 + nj * 16 + l15;
    float bv_ = (n < 1024) ? qb[n] : (n < 2048) ? kb[n - 1024] : vb[n - 2048];
    #pragma unroll
    for (int mi = 0; mi < 4; ++mi)
      #pragma unroll
      for (int r = 0; r < 4; ++r){
        int ml = wr * 64 + mi * 16 + lg * 4 + r;
        Ct[ml * 132 + wc * 64 + nj * 16 + l15] = f2bf(acc[mi][nj][r] + bv_);
      }
  }
  __syncthreads();
  {
    int row = tid >> 1;
    int c0  = (tid & 1) * 64;
    uint16_t* gp = Cg + (size_t)(m0 + row) * 3072 + n0 + c0;
    const uint16_t* sp = Ct + row * 132 + c0;
    #pragma unroll
    for (int c = 0; c < 8; ++c)
      *(uint4*)(gp + c * 8) = *(const uint4*)(sp + c * 8);
  }
}

// ---------------- k_score: S-tiles once; exp; csum; dbuf Q staging + register-direct P dump ----------------
// grid 1024 = (xcd, slot, pr, ph). A=K (rows j), B=Q (rows i): frag col(l15)=i, row(lg*4+r)=j.
// P tile layout in ws: elem (i, j) at i*64 + ((j>>3)^(i&7))*8 + (j&7)  (chunk-XOR swizzled).
// One barrier per iteration: Q(it+2) staged into alternate buffer under current compute.
__global__ __launch_bounds__(256, 4)
void k_score(const uint16_t* __restrict__ QKVg, float* __restrict__ csum,
             uint16_t* __restrict__ Pws){
  __shared__ __align__(16) uint16_t Ka[4096], Kb2[4096], Qs2[8192];
  int tid = threadIdx.x, lane = tid & 63, wid = tid >> 6;
  int l15 = lane & 15, lg = lane >> 4;
  int wr = wid >> 1, wc = wid & 1;
  int sw = l15 & 7;
  int bid = blockIdx.x, xcd = bid & 7, idx = bid >> 3;
  int bh = xcd * 8 + (idx & 7);
  int rest = idx >> 3;
  int pr = rest & 7, ph = rest >> 3;
  int b = bh >> 4, h = bh & 15;
  int jtA = pr, jtB = 15 - pr;
  const uint16_t* Qb = QKVg + (size_t)b * 1024 * 3072 + h * 64;
  const uint16_t* Kb = QKVg + (size_t)b * 1024 * 3072 + 1024 + h * 64;
  uint16_t* Pbh = Pws + (size_t)bh * 557056;

  int lr  = lane >> 3;
  int lcs = ((lane & 7) ^ lr) * 8;           // pre-swizzled source chunk
  {                                           // stage K tiles once (swizzled image, gld16)
    const uint16_t* sA = Kb + (size_t)(jtA * 64 + wid * 16 + lr) * 3072 + lcs;
    const uint16_t* sB = Kb + (size_t)(jtB * 64 + wid * 16 + lr) * 3072 + lcs;
    gld16(sA, Ka + wid * 16 * 64);
    gld16(sA + (size_t)8 * 3072, Ka + (wid * 16 + 8) * 64);
    gld16(sB, Kb2 + wid * 16 * 64);
    gld16(sB + (size_t)8 * 3072, Kb2 + (wid * 16 + 8) * 64);
  }
  int it0 = jtA + ph;
  {                                           // prologue: Q(it0) -> buf 0
    const uint16_t* sQ = Qb + (size_t)(it0 * 64 + wid * 16 + lr) * 3072 + lcs;
    gld16(sQ, Qs2 + wid * 16 * 64);
    gld16(sQ + (size_t)8 * 3072, Qs2 + (wid * 16 + 8) * 64);
  }
  __syncthreads();                            // K + Q(it0) resident
  int cur = 0;
  v4f cpA[2] = {vzero(), vzero()}, cpB[2] = {vzero(), vzero()};
  for (int it = it0; it < 16; it += 2){
    if (it + 2 < 16){                         // issue next Q stage under this iter's compute
      uint16_t* qd = Qs2 + (cur ^ 1) * 4096;
      const uint16_t* sQ = Qb + (size_t)((it + 2) * 64 + wid * 16 + lr) * 3072 + lcs;
      gld16(sQ, qd + wid * 16 * 64);
      gld16(sQ + (size_t)8 * 3072, qd + (wid * 16 + 8) * 64);
    }
    const uint16_t* Qcur = Qs2 + cur * 4096;
    bool doB = (it >= jtB);
    v4f sa[2][2], sb[2][2];
    #pragma unroll
    for (int a = 0; a < 2; ++a)
      #pragma unroll
      for (int c = 0; c < 2; ++c){ sa[a][c] = vzero(); sb[a][c] = vzero(); }
    #pragma unroll
    for (int kc = 0; kc < 2; ++kc){
      int cs = ((kc * 4 + lg) ^ sw) * 8;
      v8bf aq[2], k1[2], k2[2];
      #pragma unroll
      for (int ni = 0; ni < 2; ++ni)
        aq[ni] = *(const v8bf*)(Qcur + (wc * 32 + ni * 16 + l15) * 64 + cs);
      #pragma unroll
      for (int mj = 0; mj < 2; ++mj)
        k1[mj] = *(const v8bf*)(Ka + (wr * 32 + mj * 16 + l15) * 64 + cs);
      __builtin_amdgcn_s_setprio(1);
      #pragma unroll
      for (int mj = 0; mj < 2; ++mj)
        #pragma unroll
        for (int ni = 0; ni < 2; ++ni)
          sa[mj][ni] = __builtin_amdgcn_mfma_f32_16x16x32_bf16(k1[mj], aq[ni], sa[mj][ni], 0, 0, 0);
      __builtin_amdgcn_s_setprio(0);
      if (doB){
        #pragma unroll
        for (int mj = 0; mj < 2; ++mj)
          k2[mj] = *(const v8bf*)(Kb2 + (wr * 32 + mj * 16 + l15) * 64 + cs);
        __builtin_amdgcn_s_setprio(1);
        #pragma unroll
        for (int mj = 0; mj < 2; ++mj)
          #pragma unroll
          for (int ni = 0; ni < 2; ++ni)
            sb[mj][ni] = __builtin_amdgcn_mfma_f32_16x16x32_bf16(k2[mj], aq[ni], sb[mj][ni], 0, 0, 0);
        __builtin_amdgcn_s_setprio(0);
      }
    }
    bool diagA = (it == jtA), diagB = (it == jtB);
    int tri = it * (it + 1) / 2;
    uint16_t* dA = Pbh + (size_t)(tri + jtA) * 4096;
    uint16_t* dB = Pbh + (size_t)(tri + jtB) * 4096;
    #pragma unroll
    for (int mj = 0; mj < 2; ++mj)
      #pragma unroll
      for (int ni = 0; ni < 2; ++ni){
        int iL = wc * 32 + ni * 16 + l15;
        int jb = wr * 32 + mj * 16 + lg * 4;
        int off = iL * 64 + (((jb >> 3) ^ (iL & 7)) * 8) + (jb & 7);
        {
          float e0 = (!diagA || jb + 0 <= iL) ? __expf(sa[mj][ni][0] * 0.03125f) : 0.f;
          float e1 = (!diagA || jb + 1 <= iL) ? __expf(sa[mj][ni][1] * 0.03125f) : 0.f;
          float e2 = (!diagA || jb + 2 <= iL) ? __expf(sa[mj][ni][2] * 0.03125f) : 0.f;
          float e3 = (!diagA || jb + 3 <= iL) ? __expf(sa[mj][ni][3] * 0.03125f) : 0.f;
          v4f e4 = {e0, e1, e2, e3};
          cpA[mj] += e4;
          uint2 pk;
          pk.x = (uint32_t)f2bf(e0) | ((uint32_t)f2bf(e1) << 16);
          pk.y = (uint32_t)f2bf(e2) | ((uint32_t)f2bf(e3) << 16);
          *(uint2*)(dA + off) = pk;
        }
        if (doB){
          float e0 = (!diagB || jb + 0 <= iL) ? __expf(sb[mj][ni][0] * 0.03125f) : 0.f;
          float e1 = (!diagB || jb + 1 <= iL) ? __expf(sb[mj][ni][1] * 0.03125f) : 0.f;
          float e2 = (!diagB || jb + 2 <= iL) ? __expf(sb[mj][ni][2] * 0.03125f) : 0.f;
          float e3 = (!diagB || jb + 3 <= iL) ? __expf(sb[mj][ni][3] * 0.03125f) : 0.f;
          v4f e4 = {e0, e1, e2, e3};
          cpB[mj] += e4;
          uint2 pk;
          pk.x = (uint32_t)f2bf(e0) | ((uint32_t)f2bf(e1) << 16);
          pk.y = (uint32_t)f2bf(e2) | ((uint32_t)f2bf(e3) << 16);
          *(uint2*)(dB + off) = pk;
        }
      }
    __syncthreads();                          // Q(it+2) landed; Qs2[cur] free for overwrite
    cur ^= 1;
  }
  // csum: reduce over i (l15 lanes), then atomicAdd per j
  #pragma unroll
  for (int mj = 0; mj < 2; ++mj)
    #pragma unroll
    for (int m = 1; m <= 8; m <<= 1)
      #pragma unroll
      for (int r = 0; r < 4; ++r){
        cpA[mj][r] += __shfl_xor(cpA[mj][r], m, 64);
        cpB[mj][r] += __shfl_xor(cpB[mj][r], m, 64);
      }
  if (l15 == 0){
    #pragma unroll
    for (int mj = 0; mj < 2; ++mj)
      #pragma unroll
      for (int r = 0; r < 4; ++r){
        int jo = wr * 32 + mj * 16 + lg * 4 + r;
        atomicAdd(&csum[(size_t)bh * 1024 + jtA * 64 + jo], cpA[mj][r]);
        atomicAdd(&csum[(size_t)bh * 1024 + jtB * 64 + jo], cpB[mj][r]);
      }
  }
}

// ---------------- V' = V * mask/colsum, transposed + chunk-swizzled [bh][64 d][1024 j] ----------------
__global__ __launch_bounds__(256)
void k_vprep(const uint16_t* __restrict__ QKVg, const float* __restrict__ csum,
             const float* __restrict__ mask, uint16_t* __restrict__ Vp){
  __shared__ __align__(16) uint16_t Vs[128 * 72];
  __shared__ float scb[128];
  int tid = threadIdx.x;
  int bid = blockIdx.x, xcd = bid & 7, idx = bid >> 3;
  int bh = xcd * 8 + (idx & 7);
  int jt = idx >> 3;
  int b = bh >> 4, h = bh & 15;
  int j0 = jt * 128;
  stage64(Vs,           QKVg + ((size_t)(b * 1024 + j0)) * 3072 + 2048 + h * 64, 3072, tid);
  stage64(Vs + 64 * 72, QKVg + ((size_t)(b * 1024 + j0 + 64)) * 3072 + 2048 + h * 64, 3072, tid);
  if (tid < 128) scb[tid] = mask[b * 1024 + j0 + tid] / csum[(size_t)bh * 1024 + j0 + tid];
  __syncthreads();
  int d = tid >> 2, jc = (tid & 3) * 32;
  #pragma unroll
  for (int g8 = 0; g8 < 4; ++g8){
    union { uint16_t h[8]; uint4 v; } o;
    #pragma unroll
    for (int e = 0; e < 8; ++e){
      int j = jc + g8 * 8 + e;
      o.h[e] = f2bf(bf2f(Vs[j * 72 + d]) * scb[j]);
    }
    int jl = jc + g8 * 8;
    int wbase = jl & ~63;
    int c = (jl & 63) >> 3;
    int jphys = wbase + ((c ^ (d & 7)) * 8);
    *(uint4*)(Vp + (size_t)bh * 65536 + (size_t)d * 1024 + j0 + jphys) = o.v;
  }
}

// ---------------- k_pv: O = P @ V' — double-buffered gld16 staging, 1 barrier/tile ----------------
// grid 1024 = (xcd, slot, it). Wave w computes O rows [w*16, w*16+16).
__global__ __launch_bounds__(256, 4)
void k_pv(const uint16_t* __restrict__ Pws, const uint16_t* __restrict__ Vp,
          float* __restrict__ out){
  __shared__ __align__(16) uint16_t smem[16384];   // 2 bufs x (Pt 4096 | Vt 4096); Of f32 alias
  int tid = threadIdx.x, lane = tid & 63, l15 = lane & 15, lg = lane >> 4, wid = tid >> 6;
  int sw = l15 & 7;
  int bid = blockIdx.x, xcd = bid & 7, idx = bid >> 3;
  int bh = xcd * 8 + (idx & 7);
  int it = idx >> 3;
  int b = bh >> 4, h = bh & 15;
  const uint16_t* Pbh = Pws + (size_t)bh * 557056 + (size_t)(it * (it + 1) / 2) * 4096;
  const uint16_t* Vb  = Vp + (size_t)bh * 65536;
  v4f oacc[4];
  #pragma unroll
  for (int c = 0; c < 4; ++c) oacc[c] = vzero();

  // STAGE jt into buffer buf (4 gld16/thread: 2 P + 2 V)
  #define PV_STAGE(buf, jt) do {                                                        \
    uint16_t* Pt_ = smem + (buf) * 8192;                                                \
    uint16_t* Vt_ = Pt_ + 4096;                                                         \
    const uint16_t* ps = Pbh + (size_t)(jt) * 4096;                                     \
    gld16(ps + wid * 512 + lane * 8,        Pt_ + wid * 512);                           \
    gld16(ps + 2048 + wid * 512 + lane * 8, Pt_ + 2048 + wid * 512);                    \
    const uint16_t* vs = Vb + (size_t)(jt) * 64;                                        \
    gld16(vs + (size_t)(wid * 8 + (lane >> 3)) * 1024 + (lane & 7) * 8,      Vt_ + wid * 512); \
    gld16(vs + (size_t)(32 + wid * 8 + (lane >> 3)) * 1024 + (lane & 7) * 8, Vt_ + 2048 + wid * 512); \
  } while (0)

  PV_STAGE(0, 0);
  __syncthreads();                             // buf0 complete (barrier drains vmcnt)
  int cur = 0;
  for (int jt = 0; jt <= it; ++jt){
    if (jt < it) PV_STAGE(cur ^ 1, jt + 1);    // issue next tile early (hidden under compute)
    const uint16_t* Pt = smem + cur * 8192;
    const uint16_t* Vt = Pt + 4096;
    #pragma unroll
    for (int kc = 0; kc < 2; ++kc){
      int cs = ((kc * 4 + lg) ^ sw) * 8;
      v8bf pa = *(const v8bf*)(Pt + (wid * 16 + l15) * 64 + cs);
      v8bf vb_[4];
      #pragma unroll
      for (int dj = 0; dj < 4; ++dj)
        vb_[dj] = *(const v8bf*)(Vt + (dj * 16 + l15) * 64 + cs);
      __builtin_amdgcn_s_setprio(1);
      #pragma unroll
      for (int dj = 0; dj < 4; ++dj)
        oacc[dj] = __builtin_amdgcn_mfma_f32_16x16x32_bf16(pa, vb_[dj], oacc[dj], 0, 0, 0);
      __builtin_amdgcn_s_setprio(0);
    }
    __syncthreads();                           // next-tile loads complete; cur free to overwrite
    cur ^= 1;
  }
  #undef PV_STAGE
  // epilogue: LDS-staged coalesced f32 store
  float* Of = (float*)smem;                    // 64 x 68 f32 = 17408 B
  #pragma unroll
  for (int dj = 0; dj < 4; ++dj)
    #pragma unroll
    for (int r = 0; r < 4; ++r)
      Of[(wid * 16 + lg * 4 + r) * 68 + dj * 16 + l15] = oacc[dj][r];
  __syncthreads();
  {
    int row = tid >> 2, c0 = (tid & 3) * 16;
    float* gp = out + ((size_t)(b * 1024) + it * 64 + row) * 1024 + h * 64 + c0;
    const float* sp = Of + row * 68 + c0;
    #pragma unroll
    for (int c = 0; c < 4; ++c)
      *(float4*)(gp + c * 4) = *(const float4*)(sp + c * 4);
  }
}

extern "C" void kernel_launch(void* const* d_in, const int* in_sizes, int n_in,
                              void* d_out, int out_size, void* d_ws, size_t ws_size,
                              hipStream_t stream) {
  (void)in_sizes; (void)n_in; (void)out_size; (void)ws_size;
  const float* X    = (const float*)d_in[0];
  const float* mask = (const float*)d_in[1];
  const float* Wq   = (const float*)d_in[2];
  const float* bq   = (const float*)d_in[3];
  const float* Wk   = (const float*)d_in[4];
  const float* bk   = (const float*)d_in[5];
  const float* Wv   = (const float*)d_in[6];
  const float* bv   = (const float*)d_in[7];
  const float* Aq   = (const float*)d_in[8];
  const float* Bq   = (const float*)d_in[9];
  const float* Ak   = (const float*)d_in[10];
  const float* Bk   = (const float*)d_in[11];
  const float* Av   = (const float*)d_in[12];
  const float* Bv   = (const float*)d_in[13];
  float* out = (float*)d_out;

  uint16_t* Xb   = (uint16_t*)d_ws;                        // 8 MB
  uint16_t* Weff = Xb + (size_t)4096 * 1024;               // 6 MB
  uint16_t* QKV  = Weff + (size_t)3 * 1024 * 1024;         // 24 MB
  uint16_t* Vp   = QKV + (size_t)4096 * 3072;              // 8 MB
  float*    csum = (float*)(Vp + (size_t)64 * 64 * 1024);  // 256 KB
  uint16_t* Pws  = (uint16_t*)((char*)d_ws + 48496640ULL); // 68 MB P tiles

  k_prep<<<14336, 256, 0, stream>>>(X, Xb, csum, Wq, Aq, Bq, Wk, Ak, Bk, Wv, Av, Bv, Weff);
  k_gemm<<<768, 256, 0, stream>>>(Xb, Weff, bq, bk, bv, QKV);
  k_score<<<1024, 256, 0, stream>>>(QKV, csum, Pws);
  k_vprep<<<512, 256, 0, stream>>>(QKV, csum, mask, Vp);
  k_pv<<<1024, 256, 0, stream>>>(Pws, Vp, out);
}

// Round 14
// 99.706 us; speedup vs baseline: 1.1186x; 1.0001x over previous
//
#include <hip/hip_runtime.h>
#include <stdint.h>

typedef __bf16 v8bf __attribute__((ext_vector_type(8)));
typedef float  v4f  __attribute__((ext_vector_type(4)));

__device__ __forceinline__ uint16_t f2bf(float f){
  union { float f; uint32_t u; } v; v.f = f;
  uint32_t r = v.u + 0x7FFFu + ((v.u >> 16) & 1u);
  return (uint16_t)(r >> 16);
}
__device__ __forceinline__ float bf2f(uint16_t u){
  union { uint32_t u; float f; } v; v.u = ((uint32_t)u) << 16; return v.f;
}
__device__ __forceinline__ v4f vzero(){ v4f z = {0.f,0.f,0.f,0.f}; return z; }

// async global->LDS, 16B per lane; LDS dest is wave-uniform base + lane*16
__device__ __forceinline__ void gld16(const uint16_t* __restrict__ g, uint16_t* l){
  __builtin_amdgcn_global_load_lds((const __attribute__((address_space(1))) void*)g,
                                   (__attribute__((address_space(3))) void*)l, 16, 0, 0);
}

// ---- 64x64 bf16 tile staging, LDS row stride 72 (vprep) ----
__device__ __forceinline__ void ld64(uint4 r[2], const uint16_t* __restrict__ g, int ldg, int tid){
  int row = tid >> 2, c = (tid & 3) * 16;
  r[0] = *(const uint4*)(g + (size_t)row * ldg + c);
  r[1] = *(const uint4*)(g + (size_t)row * ldg + c + 8);
}
__device__ __forceinline__ void st64(uint16_t* __restrict__ s, const uint4 r[2], int tid){
  int row = tid >> 2, c = (tid & 3) * 16;
  *(uint4*)(s + row * 72 + c) = r[0];
  *(uint4*)(s + row * 72 + c + 8) = r[1];
}
__device__ __forceinline__ void stage64(uint16_t* s, const uint16_t* g, int ldg, int tid){
  uint4 r[2]; ld64(r, g, ldg, tid); st64(s, r, tid);
}

// ---------------- fused prep: xcast + csum zero + weff ----------------
__global__ void k_prep(const float* __restrict__ X, uint16_t* __restrict__ Xb,
                       float* __restrict__ csum,
                       const float* __restrict__ Wq, const float* __restrict__ Aq, const float* __restrict__ Bq,
                       const float* __restrict__ Wk, const float* __restrict__ Ak, const float* __restrict__ Bk,
                       const float* __restrict__ Wv, const float* __restrict__ Av, const float* __restrict__ Bv,
                       uint16_t* __restrict__ Wo){
  int bid = blockIdx.x, tid = threadIdx.x;
  if (bid < 2048){
    int i = (bid * 256 + tid) * 8;
    float4 a = *(const float4*)(X + i);
    float4 b = *(const float4*)(X + i + 4);
    union { uint16_t h[8]; uint4 v; } o;
    o.h[0]=f2bf(a.x); o.h[1]=f2bf(a.y); o.h[2]=f2bf(a.z); o.h[3]=f2bf(a.w);
    o.h[4]=f2bf(b.x); o.h[5]=f2bf(b.y); o.h[6]=f2bf(b.z); o.h[7]=f2bf(b.w);
    *(uint4*)(Xb + i) = o.v;
    if (bid < 64)                       // zero csum (64*1024 f32 = 16384 float4)
      ((float4*)csum)[bid * 256 + tid] = make_float4(0.f, 0.f, 0.f, 0.f);
  } else {
    int w = bid - 2048;
    int y = w >> 12;
    const float* W  = (y == 0) ? Wq : (y == 1) ? Wk : Wv;
    const float* A  = (y == 0) ? Aq : (y == 1) ? Ak : Av;
    const float* Bm = (y == 0) ? Bq : (y == 1) ? Bk : Bv;
    int idx = (w & 4095) * 256 + tid;
    int f = idx >> 10, k = idx & 1023;
    float acc = W[idx];
    #pragma unroll
    for (int r = 0; r < 16; ++r) acc += Bm[f * 16 + r] * A[r * 1024 + k];
    Wo[(size_t)y * 1048576 + idx] = f2bf(acc);
  }
}

// ---------------- fused QKV projection GEMM (m97 structure + XOR swizzle) ----------------
__global__ __launch_bounds__(256, 4)
void k_gemm(const uint16_t* __restrict__ Ag, const uint16_t* __restrict__ Bg,
            const float* __restrict__ qb, const float* __restrict__ kb,
            const float* __restrict__ vb, uint16_t* __restrict__ Cg){
  __shared__ __align__(16) uint16_t smem[16896];
  uint16_t* As = smem;
  uint16_t* Bs = smem + 8192;
  int tid = threadIdx.x, lane = tid & 63, wid = tid >> 6;
  int l15 = lane & 15, lg = lane >> 4;
  int wr = wid >> 1, wc = wid & 1;
  int bid = blockIdx.x, xcd = bid & 7, idx = bid >> 3;
  int nb = xcd * 96 + idx;
  int mt = nb / 24, nt = nb - mt * 24;
  int m0 = mt * 128, n0 = nt * 128;

  int lr  = lane >> 3;
  int lcs = (((lane & 7) ^ lr)) * 8;
  const uint16_t* Abase = Ag + (size_t)(m0 + wid * 32 + lr) * 1024 + lcs;
  const uint16_t* Bbase = Bg + (size_t)(n0 + wid * 32 + lr) * 1024 + lcs;
  uint16_t* Alds = As + wid * 32 * 64;
  uint16_t* Blds = Bs + wid * 32 * 64;

  int sw = l15 & 7;

  v4f acc[4][4];
  #pragma unroll
  for (int a = 0; a < 4; ++a)
    #pragma unroll
    for (int c = 0; c < 4; ++c) acc[a][c] = vzero();

  for (int kk = 0; kk < 1024; kk += 64){
    __syncthreads();
    #pragma unroll
    for (int i = 0; i < 4; ++i){
      gld16(Abase + (size_t)(i * 8) * 1024 + kk, Alds + i * 8 * 64);
      gld16(Bbase + (size_t)(i * 8) * 1024 + kk, Blds + i * 8 * 64);
    }
    __syncthreads();
    #pragma unroll
    for (int kc = 0; kc < 2; ++kc){
      v8bf af[4], bfr[4];
      int cs = ((kc * 4 + lg) ^ sw) * 8;
      #pragma unroll
      for (int mi = 0; mi < 4; ++mi)
        af[mi] = *(const v8bf*)(As + (wr * 64 + mi * 16 + l15) * 64 + cs);
      #pragma unroll
      for (int nj = 0; nj < 4; ++nj)
        bfr[nj] = *(const v8bf*)(Bs + (wc * 64 + nj * 16 + l15) * 64 + cs);
      #pragma unroll
      for (int mi = 0; mi < 4; ++mi)
        #pragma unroll
        for (int nj = 0; nj < 4; ++nj)
          acc[mi][nj] = __builtin_amdgcn_mfma_f32_16x16x32_bf16(af[mi], bfr[nj], acc[mi][nj], 0, 0, 0);
    }
  }
  __syncthreads();
  uint16_t* Ct = smem;
  #pragma unroll
  for (int nj = 0; nj < 4; ++nj){
    int n = n0 + wc * 64 + nj * 16 + l15;
    float bv_ = (n < 1024) ? qb[n] : (n < 2048) ? kb[n - 1024] : vb[n - 2048];
    #pragma unroll
    for (int mi = 0; mi < 4; ++mi)
      #pragma unroll
      for (int r = 0; r < 4; ++r){
        int ml = wr * 64 + mi * 16 + lg * 4 + r;
        Ct[ml * 132 + wc * 64 + nj * 16 + l15] = f2bf(acc[mi][nj][r] + bv_);
      }
  }
  __syncthreads();
  {
    int row = tid >> 1;
    int c0  = (tid & 1) * 64;
    uint16_t* gp = Cg + (size_t)(m0 + row) * 3072 + n0 + c0;
    const uint16_t* sp = Ct + row * 132 + c0;
    #pragma unroll
    for (int c = 0; c < 8; ++c)
      *(uint4*)(gp + c * 8) = *(const uint4*)(sp + c * 8);
  }
}

// ---------------- k_score: S-tiles once; exp; csum; dbuf Q staging + reg P dump ----------------
// grid 1024 = (xcd, slot, pr, ph). A=K (rows j), B=Q (rows i): frag col(l15)=i, row(lg*4+r)=j.
// P tile layout in ws: elem (i, j) at i*64 + ((j>>3)^(i&7))*8 + (j&7)  (chunk-XOR swizzled).
// K(jtA) fragments hoisted to registers (always used); K(jtB) stays in LDS (used when doB).
__global__ __launch_bounds__(256, 4)
void k_score(const uint16_t* __restrict__ QKVg, float* __restrict__ csum,
             uint16_t* __restrict__ Pws){
  __shared__ __align__(16) uint16_t Ka[4096], Kb2[4096], Qs2[8192];
  int tid = threadIdx.x, lane = tid & 63, wid = tid >> 6;
  int l15 = lane & 15, lg = lane >> 4;
  int wr = wid >> 1, wc = wid & 1;
  int sw = l15 & 7;
  int bid = blockIdx.x, xcd = bid & 7, idx = bid >> 3;
  int bh = xcd * 8 + (idx & 7);
  int rest = idx >> 3;
  int pr = rest & 7, ph = rest >> 3;
  int b = bh >> 4, h = bh & 15;
  int jtA = pr, jtB = 15 - pr;
  const uint16_t* Qb = QKVg + (size_t)b * 1024 * 3072 + h * 64;
  const uint16_t* Kb = QKVg + (size_t)b * 1024 * 3072 + 1024 + h * 64;
  uint16_t* Pbh = Pws + (size_t)bh * 557056;

  int lr  = lane >> 3;
  int lcs = ((lane & 7) ^ lr) * 8;           // pre-swizzled source chunk
  {                                           // stage K tiles once (swizzled image, gld16)
    const uint16_t* sA = Kb + (size_t)(jtA * 64 + wid * 16 + lr) * 3072 + lcs;
    const uint16_t* sB = Kb + (size_t)(jtB * 64 + wid * 16 + lr) * 3072 + lcs;
    gld16(sA, Ka + wid * 16 * 64);
    gld16(sA + (size_t)8 * 3072, Ka + (wid * 16 + 8) * 64);
    gld16(sB, Kb2 + wid * 16 * 64);
    gld16(sB + (size_t)8 * 3072, Kb2 + (wid * 16 + 8) * 64);
  }
  int it0 = jtA + ph;
  {                                           // prologue: Q(it0) -> buf 0
    const uint16_t* sQ = Qb + (size_t)(it0 * 64 + wid * 16 + lr) * 3072 + lcs;
    gld16(sQ, Qs2 + wid * 16 * 64);
    gld16(sQ + (size_t)8 * 3072, Qs2 + (wid * 16 + 8) * 64);
  }
  __syncthreads();                            // K + Q(it0) resident
  // hoist K(jtA) fragments to registers: 8 v8bf = 32 VGPR, freed from per-iter LDS reads
  v8bf k1r[2][2];
  #pragma unroll
  for (int kc = 0; kc < 2; ++kc){
    int cs = ((kc * 4 + lg) ^ sw) * 8;
    #pragma unroll
    for (int mj = 0; mj < 2; ++mj)
      k1r[kc][mj] = *(const v8bf*)(Ka + (wr * 32 + mj * 16 + l15) * 64 + cs);
  }
  int cur = 0;
  v4f cpA[2] = {vzero(), vzero()}, cpB[2] = {vzero(), vzero()};
  for (int it = it0; it < 16; it += 2){
    if (it + 2 < 16){                         // issue next Q stage under this iter's compute
      uint16_t* qd = Qs2 + (cur ^ 1) * 4096;
      const uint16_t* sQ = Qb + (size_t)((it + 2) * 64 + wid * 16 + lr) * 3072 + lcs;
      gld16(sQ, qd + wid * 16 * 64);
      gld16(sQ + (size_t)8 * 3072, qd + (wid * 16 + 8) * 64);
    }
    const uint16_t* Qcur = Qs2 + cur * 4096;
    bool doB = (it >= jtB);
    v4f sa[2][2], sb[2][2];
    #pragma unroll
    for (int a = 0; a < 2; ++a)
      #pragma unroll
      for (int c = 0; c < 2; ++c){ sa[a][c] = vzero(); sb[a][c] = vzero(); }
    #pragma unroll
    for (int kc = 0; kc < 2; ++kc){
      int cs = ((kc * 4 + lg) ^ sw) * 8;
      v8bf aq[2], k2[2];
      #pragma unroll
      for (int ni = 0; ni < 2; ++ni)
        aq[ni] = *(const v8bf*)(Qcur + (wc * 32 + ni * 16 + l15) * 64 + cs);
      __builtin_amdgcn_s_setprio(1);
      #pragma unroll
      for (int mj = 0; mj < 2; ++mj)
        #pragma unroll
        for (int ni = 0; ni < 2; ++ni)
          sa[mj][ni] = __builtin_amdgcn_mfma_f32_16x16x32_bf16(k1r[kc][mj], aq[ni], sa[mj][ni], 0, 0, 0);
      __builtin_amdgcn_s_setprio(0);
      if (doB){
        #pragma unroll
        for (int mj = 0; mj < 2; ++mj)
          k2[mj] = *(const v8bf*)(Kb2 + (wr * 32 + mj * 16 + l15) * 64 + cs);
        __builtin_amdgcn_s_setprio(1);
        #pragma unroll
        for (int mj = 0; mj < 2; ++mj)
          #pragma unroll
          for (int ni = 0; ni < 2; ++ni)
            sb[mj][ni] = __builtin_amdgcn_mfma_f32_16x16x32_bf16(k2[mj], aq[ni], sb[mj][ni], 0, 0, 0);
        __builtin_amdgcn_s_setprio(0);
      }
    }
    bool diagA = (it == jtA), diagB = (it == jtB);
    int tri = it * (it + 1) / 2;
    uint16_t* dA = Pbh + (size_t)(tri + jtA) * 4096;
    uint16_t* dB = Pbh + (size_t)(tri + jtB) * 4096;
    #pragma unroll
    for (int mj = 0; mj < 2; ++mj)
      #pragma unroll
      for (int ni = 0; ni < 2; ++ni){
        int iL = wc * 32 + ni * 16 + l15;
        int jb = wr * 32 + mj * 16 + lg * 4;
        int off = iL * 64 + (((jb >> 3) ^ (iL & 7)) * 8) + (jb & 7);
        {
          float e0 = (!diagA || jb + 0 <= iL) ? __expf(sa[mj][ni][0] * 0.03125f) : 0.f;
          float e1 = (!diagA || jb + 1 <= iL) ? __expf(sa[mj][ni][1] * 0.03125f) : 0.f;
          float e2 = (!diagA || jb + 2 <= iL) ? __expf(sa[mj][ni][2] * 0.03125f) : 0.f;
          float e3 = (!diagA || jb + 3 <= iL) ? __expf(sa[mj][ni][3] * 0.03125f) : 0.f;
          v4f e4 = {e0, e1, e2, e3};
          cpA[mj] += e4;
          uint2 pk;
          pk.x = (uint32_t)f2bf(e0) | ((uint32_t)f2bf(e1) << 16);
          pk.y = (uint32_t)f2bf(e2) | ((uint32_t)f2bf(e3) << 16);
          *(uint2*)(dA + off) = pk;
        }
        if (doB){
          float e0 = (!diagB || jb + 0 <= iL) ? __expf(sb[mj][ni][0] * 0.03125f) : 0.f;
          float e1 = (!diagB || jb + 1 <= iL) ? __expf(sb[mj][ni][1] * 0.03125f) : 0.f;
          float e2 = (!diagB || jb + 2 <= iL) ? __expf(sb[mj][ni][2] * 0.03125f) : 0.f;
          float e3 = (!diagB || jb + 3 <= iL) ? __expf(sb[mj][ni][3] * 0.03125f) : 0.f;
          v4f e4 = {e0, e1, e2, e3};
          cpB[mj] += e4;
          uint2 pk;
          pk.x = (uint32_t)f2bf(e0) | ((uint32_t)f2bf(e1) << 16);
          pk.y = (uint32_t)f2bf(e2) | ((uint32_t)f2bf(e3) << 16);
          *(uint2*)(dB + off) = pk;
        }
      }
    __syncthreads();                          // Q(it+2) landed; Qs2[cur] free for overwrite
    cur ^= 1;
  }
  // csum: reduce over i (l15 lanes), then atomicAdd per j
  #pragma unroll
  for (int mj = 0; mj < 2; ++mj)
    #pragma unroll
    for (int m = 1; m <= 8; m <<= 1)
      #pragma unroll
      for (int r = 0; r < 4; ++r){
        cpA[mj][r] += __shfl_xor(cpA[mj][r], m, 64);
        cpB[mj][r] += __shfl_xor(cpB[mj][r], m, 64);
      }
  if (l15 == 0){
    #pragma unroll
    for (int mj = 0; mj < 2; ++mj)
      #pragma unroll
      for (int r = 0; r < 4; ++r){
        int jo = wr * 32 + mj * 16 + lg * 4 + r;
        atomicAdd(&csum[(size_t)bh * 1024 + jtA * 64 + jo], cpA[mj][r]);
        atomicAdd(&csum[(size_t)bh * 1024 + jtB * 64 + jo], cpB[mj][r]);
      }
  }
}

// ---------------- V' = V * mask/colsum, transposed + chunk-swizzled [bh][64 d][1024 j] ----------------
__global__ __launch_bounds__(256)
void k_vprep(const uint16_t* __restrict__ QKVg, const float* __restrict__ csum,
             const float* __restrict__ mask, uint16_t* __restrict__ Vp){
  __shared__ __align__(16) uint16_t Vs[128 * 72];
  __shared__ float scb[128];
  int tid = threadIdx.x;
  int bid = blockIdx.x, xcd = bid & 7, idx = bid >> 3;
  int bh = xcd * 8 + (idx & 7);
  int jt = idx >> 3;
  int b = bh >> 4, h = bh & 15;
  int j0 = jt * 128;
  stage64(Vs,           QKVg + ((size_t)(b * 1024 + j0)) * 3072 + 2048 + h * 64, 3072, tid);
  stage64(Vs + 64 * 72, QKVg + ((size_t)(b * 1024 + j0 + 64)) * 3072 + 2048 + h * 64, 3072, tid);
  if (tid < 128) scb[tid] = mask[b * 1024 + j0 + tid] / csum[(size_t)bh * 1024 + j0 + tid];
  __syncthreads();
  int d = tid >> 2, jc = (tid & 3) * 32;
  #pragma unroll
  for (int g8 = 0; g8 < 4; ++g8){
    union { uint16_t h[8]; uint4 v; } o;
    #pragma unroll
    for (int e = 0; e < 8; ++e){
      int j = jc + g8 * 8 + e;
      o.h[e] = f2bf(bf2f(Vs[j * 72 + d]) * scb[j]);
    }
    int jl = jc + g8 * 8;
    int wbase = jl & ~63;
    int c = (jl & 63) >> 3;
    int jphys = wbase + ((c ^ (d & 7)) * 8);
    *(uint4*)(Vp + (size_t)bh * 65536 + (size_t)d * 1024 + j0 + jphys) = o.v;
  }
}

// ---------------- k_pv: O = P @ V' — double-buffered gld16 staging, 1 barrier/tile ----------------
// grid 1024 = (xcd, slot, it). Wave w computes O rows [w*16, w*16+16).
__global__ __launch_bounds__(256, 4)
void k_pv(const uint16_t* __restrict__ Pws, const uint16_t* __restrict__ Vp,
          float* __restrict__ out){
  __shared__ __align__(16) uint16_t smem[16384];   // 2 bufs x (Pt 4096 | Vt 4096); Of f32 alias
  int tid = threadIdx.x, lane = tid & 63, l15 = lane & 15, lg = lane >> 4, wid = tid >> 6;
  int sw = l15 & 7;
  int bid = blockIdx.x, xcd = bid & 7, idx = bid >> 3;
  int bh = xcd * 8 + (idx & 7);
  int it = idx >> 3;
  int b = bh >> 4, h = bh & 15;
  const uint16_t* Pbh = Pws + (size_t)bh * 557056 + (size_t)(it * (it + 1) / 2) * 4096;
  const uint16_t* Vb  = Vp + (size_t)bh * 65536;
  v4f oacc[4];
  #pragma unroll
  for (int c = 0; c < 4; ++c) oacc[c] = vzero();

  // STAGE jt into buffer buf (4 gld16/thread: 2 P + 2 V)
  #define PV_STAGE(buf, jt) do {                                                        \
    uint16_t* Pt_ = smem + (buf) * 8192;                                                \
    uint16_t* Vt_ = Pt_ + 4096;                                                         \
    const uint16_t* ps = Pbh + (size_t)(jt) * 4096;                                     \
    gld16(ps + wid * 512 + lane * 8,        Pt_ + wid * 512);                           \
    gld16(ps + 2048 + wid * 512 + lane * 8, Pt_ + 2048 + wid * 512);                    \
    const uint16_t* vs = Vb + (size_t)(jt) * 64;                                        \
    gld16(vs + (size_t)(wid * 8 + (lane >> 3)) * 1024 + (lane & 7) * 8,      Vt_ + wid * 512); \
    gld16(vs + (size_t)(32 + wid * 8 + (lane >> 3)) * 1024 + (lane & 7) * 8, Vt_ + 2048 + wid * 512); \
  } while (0)

  PV_STAGE(0, 0);
  __syncthreads();                             // buf0 complete (barrier drains vmcnt)
  int cur = 0;
  for (int jt = 0; jt <= it; ++jt){
    if (jt < it) PV_STAGE(cur ^ 1, jt + 1);    // issue next tile early (hidden under compute)
    const uint16_t* Pt = smem + cur * 8192;
    const uint16_t* Vt = Pt + 4096;
    #pragma unroll
    for (int kc = 0; kc < 2; ++kc){
      int cs = ((kc * 4 + lg) ^ sw) * 8;
      v8bf pa = *(const v8bf*)(Pt + (wid * 16 + l15) * 64 + cs);
      v8bf vb_[4];
      #pragma unroll
      for (int dj = 0; dj < 4; ++dj)
        vb_[dj] = *(const v8bf*)(Vt + (dj * 16 + l15) * 64 + cs);
      __builtin_amdgcn_s_setprio(1);
      #pragma unroll
      for (int dj = 0; dj < 4; ++dj)
        oacc[dj] = __builtin_amdgcn_mfma_f32_16x16x32_bf16(pa, vb_[dj], oacc[dj], 0, 0, 0);
      __builtin_amdgcn_s_setprio(0);
    }
    __syncthreads();                           // next-tile loads complete; cur free to overwrite
    cur ^= 1;
  }
  #undef PV_STAGE
  // epilogue: LDS-staged coalesced f32 store
  float* Of = (float*)smem;                    // 64 x 68 f32 = 17408 B
  #pragma unroll
  for (int dj = 0; dj < 4; ++dj)
    #pragma unroll
    for (int r = 0; r < 4; ++r)
      Of[(wid * 16 + lg * 4 + r) * 68 + dj * 16 + l15] = oacc[dj][r];
  __syncthreads();
  {
    int row = tid >> 2, c0 = (tid & 3) * 16;
    float* gp = out + ((size_t)(b * 1024) + it * 64 + row) * 1024 + h * 64 + c0;
    const float* sp = Of + row * 68 + c0;
    #pragma unroll
    for (int c = 0; c < 4; ++c)
      *(float4*)(gp + c * 4) = *(const float4*)(sp + c * 4);
  }
}

extern "C" void kernel_launch(void* const* d_in, const int* in_sizes, int n_in,
                              void* d_out, int out_size, void* d_ws, size_t ws_size,
                              hipStream_t stream) {
  (void)in_sizes; (void)n_in; (void)out_size; (void)ws_size;
  const float* X    = (const float*)d_in[0];
  const float* mask = (const float*)d_in[1];
  const float* Wq   = (const float*)d_in[2];
  const float* bq   = (const float*)d_in[3];
  const float* Wk   = (const float*)d_in[4];
  const float* bk   = (const float*)d_in[5];
  const float* Wv   = (const float*)d_in[6];
  const float* bv   = (const float*)d_in[7];
  const float* Aq   = (const float*)d_in[8];
  const float* Bq   = (const float*)d_in[9];
  const float* Ak   = (const float*)d_in[10];
  const float* Bk   = (const float*)d_in[11];
  const float* Av   = (const float*)d_in[12];
  const float* Bv   = (const float*)d_in[13];
  float* out = (float*)d_out;

  uint16_t* Xb   = (uint16_t*)d_ws;                        // 8 MB
  uint16_t* Weff = Xb + (size_t)4096 * 1024;               // 6 MB
  uint16_t* QKV  = Weff + (size_t)3 * 1024 * 1024;         // 24 MB
  uint16_t* Vp   = QKV + (size_t)4096 * 3072;              // 8 MB
  float*    csum = (float*)(Vp + (size_t)64 * 64 * 1024);  // 256 KB
  uint16_t* Pws  = (uint16_t*)((char*)d_ws + 48496640ULL); // 68 MB P tiles

  k_prep<<<14336, 256, 0, stream>>>(X, Xb, csum, Wq, Aq, Bq, Wk, Ak, Bk, Wv, Av, Bv, Weff);
  k_gemm<<<768, 256, 0, stream>>>(Xb, Weff, bq, bk, bv, QKV);
  k_score<<<1024, 256, 0, stream>>>(QKV, csum, Pws);
  k_vprep<<<512, 256, 0, stream>>>(QKV, csum, mask, Vp);
  k_pv<<<1024, 256, 0, stream>>>(Pws, Vp, out);
}